// Round 4
// baseline (164.501 us; speedup 1.0000x reference)
//
#include <hip/hip_runtime.h>
#include <hip/hip_bf16.h>
#include <float.h>

#define DEPTH_PARAM 0.5f
#define LENGTH_PENALTY 1.5f

__global__ void init_out_kernel(float* out) { out[0] = 0.0f; }

// TWO waves per batch row (256-thread block = 4 waves = 2 rows).
// Compile-time C: all float4 loads for the row-half are issued back-to-back
// (12 outstanding global_load_dwordx4 per thread) before the compare chains,
// maximizing memory-level parallelism. Tail: one 8-lane group per tree level.
// Row totals are atomicAdd'ed into out[0] (pre-zeroed by init kernel).
template<int C>
__global__ __launch_bounds__(256) void hier_row_kernel_t(
    const float* __restrict__ y_pred,
    const float* __restrict__ y_true,
    const float* __restrict__ class_weights,
    const int* __restrict__ path_ids,
    const int* __restrict__ path_len,
    const int* __restrict__ sib_start,
    const int* __restrict__ sib_size,
    float* __restrict__ out,
    int D, int Bsz)
{
    constexpr int C4  = C >> 2;
    constexpr int NIT = (C4 + 127) / 128;

    const int wid  = threadIdx.x >> 6;       // 0..3
    const int lane = threadIdx.x & 63;
    const int half = wid & 1;
    int row = blockIdx.x * 2 + (wid >> 1);
    bool edge_dup = false;
    if (row >= Bsz) { row = Bsz - 1; edge_dup = true; }

    const float* __restrict__ yp = y_pred + (size_t)row * C;
    const float* __restrict__ yt = y_true + (size_t)row * C;
    const float4* __restrict__ yp4 = (const float4*)yp;
    const float4* __restrict__ yt4 = (const float4*)yt;

    // ---- batch all loads first: max outstanding vmem ----
    float4 vv[NIT], ww[NIT];
    const int i0 = half * 64 + lane;
#pragma unroll
    for (int k = 0; k < NIT; k++) {
        const int i = i0 + k * 128;
        if (i < C4) {
            vv[k] = yp4[i];
            ww[k] = yt4[i];
        } else {
            vv[k] = make_float4(-FLT_MAX, -FLT_MAX, -FLT_MAX, -FLT_MAX);
            ww[k] = make_float4(-FLT_MAX, -FLT_MAX, -FLT_MAX, -FLT_MAX);
        }
    }

    // ---- dual argmax compare chains ----
    float bp = -FLT_MAX; int bip = 0;
    float bt = -FLT_MAX; int bit_ = 0;
#pragma unroll
    for (int k = 0; k < NIT; k++) {
        const int base = (i0 + k * 128) << 2;
        const float4 v = vv[k];
        const float4 w = ww[k];
        if (v.x > bp) { bp = v.x; bip = base + 0; }
        if (v.y > bp) { bp = v.y; bip = base + 1; }
        if (v.z > bp) { bp = v.z; bip = base + 2; }
        if (v.w > bp) { bp = v.w; bip = base + 3; }
        if (w.x > bt) { bt = w.x; bit_ = base + 0; }
        if (w.y > bt) { bt = w.y; bit_ = base + 1; }
        if (w.z > bt) { bt = w.z; bit_ = base + 2; }
        if (w.w > bt) { bt = w.w; bit_ = base + 3; }
    }
    // scalar remainder only if C % 4 != 0 (dead code for C=2728)
    if constexpr ((C & 3) != 0) {
        for (int c = (C4 << 2) + half * 64 + lane; c < C; c += 128) {
            float v = yp[c]; if (v > bp) { bp = v; bip = c; }
            float w = yt[c]; if (w > bt) { bt = w; bit_ = c; }
        }
    }

    // ---- butterfly reduce within wave (all lanes get max, min-index) ----
    for (int m = 1; m < 64; m <<= 1) {
        float ov = __shfl_xor(bp, m); int oi = __shfl_xor(bip, m);
        if (ov > bp || (ov == bp && oi < bip)) { bp = ov; bip = oi; }
        float ow = __shfl_xor(bt, m); int oj = __shfl_xor(bit_, m);
        if (ow > bt || (ow == bt && oj < bit_)) { bt = ow; bit_ = oj; }
    }

    // ---- merge the two waves of this row via LDS ----
    __shared__ float s_v[4][2];
    __shared__ int   s_i[4][2];
    if (lane == 0) {
        s_v[wid][0] = bp;  s_i[wid][0] = bip;
        s_v[wid][1] = bt;  s_i[wid][1] = bit_;
    }
    __syncthreads();
    {
        const int pw = wid ^ 1;
        float ov = s_v[pw][0]; int oi = s_i[pw][0];
        if (ov > bp || (ov == bp && oi < bip)) { bp = ov; bip = oi; }
        float ow = s_v[pw][1]; int oj = s_i[pw][1];
        if (ow > bt || (ow == bt && oj < bit_)) { bt = ow; bit_ = oj; }
    }

    // ---- tail: first wave of the pair only; skip duplicated edge rows ----
    if (half == 0 && !edge_dup) {
        const int pred_top = bip;
        const int true_top = bit_;
        const int lp = path_len[pred_top];
        const int lt = path_len[true_top];
        const int lmin = lp < lt ? lp : lt;

        const int l = lane >> 3;             // level for this 8-lane group
        const int j = lane & 7;
        float e = 0.0f;
        int sz = 0;
        if (l < lmin) {
            const int st = sib_start[true_top * D + l];
            sz = sib_size[true_top * D + l];
            if (j < sz) e = expf(yp[st + j]);
        }
        e += __shfl_xor(e, 1);
        e += __shfl_xor(e, 2);
        e += __shfl_xor(e, 4);
        float contrib = 0.0f;
        if (l < lmin && j == 0) {
            const float s = e + (float)(C - sz);   // masked-out -> exp(0)=1
            const int tix = path_ids[true_top * D + l];
            const float ce = logf(s) - yp[tix];
            const float lw = expf(-DEPTH_PARAM * (float)(lt - l - 1));
            contrib = lw * ce;
        }
        contrib += __shfl_xor(contrib, 8);
        contrib += __shfl_xor(contrib, 16);
        contrib += __shfl_xor(contrib, 32);

        if (lane == 0) {
            const float diff = fabsf((float)(lp - lt));
            const float total = contrib * (LENGTH_PENALTY * diff) * class_weights[true_top];
            atomicAdd(out, total / (float)Bsz);
        }
    }
}

// Generic fallback (runtime C) — same structure, strided loop.
__global__ __launch_bounds__(256) void hier_row_kernel_g(
    const float* __restrict__ y_pred,
    const float* __restrict__ y_true,
    const float* __restrict__ class_weights,
    const int* __restrict__ path_ids,
    const int* __restrict__ path_len,
    const int* __restrict__ sib_start,
    const int* __restrict__ sib_size,
    float* __restrict__ out,
    int C, int D, int Bsz)
{
    const int wid  = threadIdx.x >> 6;
    const int lane = threadIdx.x & 63;
    const int half = wid & 1;
    int row = blockIdx.x * 2 + (wid >> 1);
    bool edge_dup = false;
    if (row >= Bsz) { row = Bsz - 1; edge_dup = true; }

    const float* __restrict__ yp = y_pred + (size_t)row * C;
    const float* __restrict__ yt = y_true + (size_t)row * C;
    const float4* __restrict__ yp4 = (const float4*)yp;
    const float4* __restrict__ yt4 = (const float4*)yt;

    float bp = -FLT_MAX; int bip = 0;
    float bt = -FLT_MAX; int bit_ = 0;
    const int C4 = C >> 2;
    for (int i = half * 64 + lane; i < C4; i += 128) {
        float4 v = yp4[i];
        float4 w = yt4[i];
        int base = i << 2;
        if (v.x > bp) { bp = v.x; bip = base + 0; }
        if (v.y > bp) { bp = v.y; bip = base + 1; }
        if (v.z > bp) { bp = v.z; bip = base + 2; }
        if (v.w > bp) { bp = v.w; bip = base + 3; }
        if (w.x > bt) { bt = w.x; bit_ = base + 0; }
        if (w.y > bt) { bt = w.y; bit_ = base + 1; }
        if (w.z > bt) { bt = w.z; bit_ = base + 2; }
        if (w.w > bt) { bt = w.w; bit_ = base + 3; }
    }
    for (int c = (C4 << 2) + half * 64 + lane; c < C; c += 128) {
        float v = yp[c]; if (v > bp) { bp = v; bip = c; }
        float w = yt[c]; if (w > bt) { bt = w; bit_ = c; }
    }
    for (int m = 1; m < 64; m <<= 1) {
        float ov = __shfl_xor(bp, m); int oi = __shfl_xor(bip, m);
        if (ov > bp || (ov == bp && oi < bip)) { bp = ov; bip = oi; }
        float ow = __shfl_xor(bt, m); int oj = __shfl_xor(bit_, m);
        if (ow > bt || (ow == bt && oj < bit_)) { bt = ow; bit_ = oj; }
    }
    __shared__ float s_v[4][2];
    __shared__ int   s_i[4][2];
    if (lane == 0) {
        s_v[wid][0] = bp;  s_i[wid][0] = bip;
        s_v[wid][1] = bt;  s_i[wid][1] = bit_;
    }
    __syncthreads();
    {
        const int pw = wid ^ 1;
        float ov = s_v[pw][0]; int oi = s_i[pw][0];
        if (ov > bp || (ov == bp && oi < bip)) { bp = ov; bip = oi; }
        float ow = s_v[pw][1]; int oj = s_i[pw][1];
        if (ow > bt || (ow == bt && oj < bit_)) { bt = ow; bit_ = oj; }
    }
    if (half == 0 && !edge_dup) {
        const int pred_top = bip;
        const int true_top = bit_;
        const int lp = path_len[pred_top];
        const int lt = path_len[true_top];
        const int lmin = lp < lt ? lp : lt;
        const int l = lane >> 3;
        const int j = lane & 7;
        float e = 0.0f;
        int sz = 0;
        if (l < lmin) {
            const int st = sib_start[true_top * D + l];
            sz = sib_size[true_top * D + l];
            if (j < sz) e = expf(yp[st + j]);
        }
        e += __shfl_xor(e, 1);
        e += __shfl_xor(e, 2);
        e += __shfl_xor(e, 4);
        float contrib = 0.0f;
        if (l < lmin && j == 0) {
            const float s = e + (float)(C - sz);
            const int tix = path_ids[true_top * D + l];
            const float ce = logf(s) - yp[tix];
            const float lw = expf(-DEPTH_PARAM * (float)(lt - l - 1));
            contrib = lw * ce;
        }
        contrib += __shfl_xor(contrib, 8);
        contrib += __shfl_xor(contrib, 16);
        contrib += __shfl_xor(contrib, 32);
        if (lane == 0) {
            const float diff = fabsf((float)(lp - lt));
            const float total = contrib * (LENGTH_PENALTY * diff) * class_weights[true_top];
            atomicAdd(out, total / (float)Bsz);
        }
    }
}

extern "C" void kernel_launch(void* const* d_in, const int* in_sizes, int n_in,
                              void* d_out, int out_size, void* d_ws, size_t ws_size,
                              hipStream_t stream) {
    const float* y_pred        = (const float*)d_in[0];
    const float* y_true        = (const float*)d_in[1];
    const float* class_weights = (const float*)d_in[2];
    const int*   path_ids      = (const int*)d_in[3];
    const int*   path_len      = (const int*)d_in[4];
    const int*   sib_start     = (const int*)d_in[5];
    const int*   sib_size      = (const int*)d_in[6];
    float* out = (float*)d_out;

    const int C = in_sizes[2];            // 2728
    const int D = in_sizes[3] / C;        // 5
    const int B = in_sizes[0] / C;        // 4096

    const int grid = (B + 1) / 2;         // 2 rows/block, 2 waves/row
    init_out_kernel<<<1, 1, 0, stream>>>(out);
    if (C == 2728) {
        hier_row_kernel_t<2728><<<grid, 256, 0, stream>>>(
            y_pred, y_true, class_weights, path_ids, path_len,
            sib_start, sib_size, out, D, B);
    } else {
        hier_row_kernel_g<<<grid, 256, 0, stream>>>(
            y_pred, y_true, class_weights, path_ids, path_len,
            sib_start, sib_size, out, C, D, B);
    }
}

// Round 5
// 163.151 us; speedup vs baseline: 1.0083x; 1.0083x over previous
//
#include <hip/hip_runtime.h>
#include <hip/hip_bf16.h>
#include <float.h>

#define DEPTH_PARAM 0.5f
#define LENGTH_PENALTY 1.5f

__global__ void init_out_kernel(float* out) { out[0] = 0.0f; }

// TWO waves per batch row (256-thread block = 4 waves = 2 rows).
// Chunked prefetch: 3 iterations' loads (6 x global_load_dwordx4) issued
// back-to-back, then compares — 24 VGPRs of live data, safely under the
// spill cliff that killed the full-batch version (R4: 32 VGPRs + scratch).
// Tail: one 8-lane group per tree level. Mean fused via atomicAdd.
template<int C>
__global__ __launch_bounds__(256) void hier_row_kernel_t(
    const float* __restrict__ y_pred,
    const float* __restrict__ y_true,
    const float* __restrict__ class_weights,
    const int* __restrict__ path_ids,
    const int* __restrict__ path_len,
    const int* __restrict__ sib_start,
    const int* __restrict__ sib_size,
    float* __restrict__ out,
    int D, int Bsz)
{
    constexpr int C4  = C >> 2;              // 682 for C=2728
    constexpr int NIT = (C4 + 127) / 128;    // 6
    constexpr int CH  = 3;                   // chunk size (6 float4 live)

    const int wid  = threadIdx.x >> 6;       // 0..3
    const int lane = threadIdx.x & 63;
    const int half = wid & 1;
    int row = blockIdx.x * 2 + (wid >> 1);
    bool edge_dup = false;
    if (row >= Bsz) { row = Bsz - 1; edge_dup = true; }

    const float* __restrict__ yp = y_pred + (size_t)row * C;
    const float* __restrict__ yt = y_true + (size_t)row * C;
    const float4* __restrict__ yp4 = (const float4*)yp;
    const float4* __restrict__ yt4 = (const float4*)yt;

    const int i0 = half * 64 + lane;
    float bp = -FLT_MAX; int bip = 0;
    float bt = -FLT_MAX; int bit_ = 0;

#pragma unroll
    for (int k0 = 0; k0 < NIT; k0 += CH) {
        float4 vv[CH], ww[CH];
        // issue chunk's loads back-to-back (clamped index, no divergence)
#pragma unroll
        for (int k = 0; k < CH; k++) {
            if (k0 + k < NIT) {
                const int i  = i0 + (k0 + k) * 128;
                const int ic = i < C4 ? i : C4 - 1;
                vv[k] = yp4[ic];
                ww[k] = yt4[ic];
            }
        }
        // compares
#pragma unroll
        for (int k = 0; k < CH; k++) {
            if (k0 + k < NIT) {
                const int i = i0 + (k0 + k) * 128;
                float4 v = vv[k];
                float4 w = ww[k];
                if (i >= C4) {                 // sentinel for clamped lanes
                    v = make_float4(-FLT_MAX, -FLT_MAX, -FLT_MAX, -FLT_MAX);
                    w = v;
                }
                const int base = i << 2;
                if (v.x > bp) { bp = v.x; bip = base + 0; }
                if (v.y > bp) { bp = v.y; bip = base + 1; }
                if (v.z > bp) { bp = v.z; bip = base + 2; }
                if (v.w > bp) { bp = v.w; bip = base + 3; }
                if (w.x > bt) { bt = w.x; bit_ = base + 0; }
                if (w.y > bt) { bt = w.y; bit_ = base + 1; }
                if (w.z > bt) { bt = w.z; bit_ = base + 2; }
                if (w.w > bt) { bt = w.w; bit_ = base + 3; }
            }
        }
    }
    if constexpr ((C & 3) != 0) {
        for (int c = (C4 << 2) + half * 64 + lane; c < C; c += 128) {
            float v = yp[c]; if (v > bp) { bp = v; bip = c; }
            float w = yt[c]; if (w > bt) { bt = w; bit_ = c; }
        }
    }

    // ---- butterfly reduce within wave ----
    for (int m = 1; m < 64; m <<= 1) {
        float ov = __shfl_xor(bp, m); int oi = __shfl_xor(bip, m);
        if (ov > bp || (ov == bp && oi < bip)) { bp = ov; bip = oi; }
        float ow = __shfl_xor(bt, m); int oj = __shfl_xor(bit_, m);
        if (ow > bt || (ow == bt && oj < bit_)) { bt = ow; bit_ = oj; }
    }

    // ---- merge the two waves of this row via LDS ----
    __shared__ float s_v[4][2];
    __shared__ int   s_i[4][2];
    if (lane == 0) {
        s_v[wid][0] = bp;  s_i[wid][0] = bip;
        s_v[wid][1] = bt;  s_i[wid][1] = bit_;
    }
    __syncthreads();
    {
        const int pw = wid ^ 1;
        float ov = s_v[pw][0]; int oi = s_i[pw][0];
        if (ov > bp || (ov == bp && oi < bip)) { bp = ov; bip = oi; }
        float ow = s_v[pw][1]; int oj = s_i[pw][1];
        if (ow > bt || (ow == bt && oj < bit_)) { bt = ow; bit_ = oj; }
    }

    // ---- tail: first wave of the pair only ----
    if (half == 0 && !edge_dup) {
        const int pred_top = bip;
        const int true_top = bit_;
        const int lp = path_len[pred_top];
        const int lt = path_len[true_top];
        const int lmin = lp < lt ? lp : lt;

        const int l = lane >> 3;             // level for this 8-lane group
        const int j = lane & 7;
        float e = 0.0f;
        int sz = 0;
        if (l < lmin) {
            const int st = sib_start[true_top * D + l];
            sz = sib_size[true_top * D + l];
            if (j < sz) e = expf(yp[st + j]);
        }
        e += __shfl_xor(e, 1);
        e += __shfl_xor(e, 2);
        e += __shfl_xor(e, 4);
        float contrib = 0.0f;
        if (l < lmin && j == 0) {
            const float s = e + (float)(C - sz);   // masked-out -> exp(0)=1
            const int tix = path_ids[true_top * D + l];
            const float ce = logf(s) - yp[tix];
            const float lw = expf(-DEPTH_PARAM * (float)(lt - l - 1));
            contrib = lw * ce;
        }
        contrib += __shfl_xor(contrib, 8);
        contrib += __shfl_xor(contrib, 16);
        contrib += __shfl_xor(contrib, 32);

        if (lane == 0) {
            const float diff = fabsf((float)(lp - lt));
            const float total = contrib * (LENGTH_PENALTY * diff) * class_weights[true_top];
            atomicAdd(out, total / (float)Bsz);
        }
    }
}

// Generic fallback (runtime C) — R3-style strided loop + fused atomic mean.
__global__ __launch_bounds__(256) void hier_row_kernel_g(
    const float* __restrict__ y_pred,
    const float* __restrict__ y_true,
    const float* __restrict__ class_weights,
    const int* __restrict__ path_ids,
    const int* __restrict__ path_len,
    const int* __restrict__ sib_start,
    const int* __restrict__ sib_size,
    float* __restrict__ out,
    int C, int D, int Bsz)
{
    const int wid  = threadIdx.x >> 6;
    const int lane = threadIdx.x & 63;
    const int half = wid & 1;
    int row = blockIdx.x * 2 + (wid >> 1);
    bool edge_dup = false;
    if (row >= Bsz) { row = Bsz - 1; edge_dup = true; }

    const float* __restrict__ yp = y_pred + (size_t)row * C;
    const float* __restrict__ yt = y_true + (size_t)row * C;
    const float4* __restrict__ yp4 = (const float4*)yp;
    const float4* __restrict__ yt4 = (const float4*)yt;

    float bp = -FLT_MAX; int bip = 0;
    float bt = -FLT_MAX; int bit_ = 0;
    const int C4 = C >> 2;
    for (int i = half * 64 + lane; i < C4; i += 128) {
        float4 v = yp4[i];
        float4 w = yt4[i];
        int base = i << 2;
        if (v.x > bp) { bp = v.x; bip = base + 0; }
        if (v.y > bp) { bp = v.y; bip = base + 1; }
        if (v.z > bp) { bp = v.z; bip = base + 2; }
        if (v.w > bp) { bp = v.w; bip = base + 3; }
        if (w.x > bt) { bt = w.x; bit_ = base + 0; }
        if (w.y > bt) { bt = w.y; bit_ = base + 1; }
        if (w.z > bt) { bt = w.z; bit_ = base + 2; }
        if (w.w > bt) { bt = w.w; bit_ = base + 3; }
    }
    for (int c = (C4 << 2) + half * 64 + lane; c < C; c += 128) {
        float v = yp[c]; if (v > bp) { bp = v; bip = c; }
        float w = yt[c]; if (w > bt) { bt = w; bit_ = c; }
    }
    for (int m = 1; m < 64; m <<= 1) {
        float ov = __shfl_xor(bp, m); int oi = __shfl_xor(bip, m);
        if (ov > bp || (ov == bp && oi < bip)) { bp = ov; bip = oi; }
        float ow = __shfl_xor(bt, m); int oj = __shfl_xor(bit_, m);
        if (ow > bt || (ow == bt && oj < bit_)) { bt = ow; bit_ = oj; }
    }
    __shared__ float s_v[4][2];
    __shared__ int   s_i[4][2];
    if (lane == 0) {
        s_v[wid][0] = bp;  s_i[wid][0] = bip;
        s_v[wid][1] = bt;  s_i[wid][1] = bit_;
    }
    __syncthreads();
    {
        const int pw = wid ^ 1;
        float ov = s_v[pw][0]; int oi = s_i[pw][0];
        if (ov > bp || (ov == bp && oi < bip)) { bp = ov; bip = oi; }
        float ow = s_v[pw][1]; int oj = s_i[pw][1];
        if (ow > bt || (ow == bt && oj < bit_)) { bt = ow; bit_ = oj; }
    }
    if (half == 0 && !edge_dup) {
        const int pred_top = bip;
        const int true_top = bit_;
        const int lp = path_len[pred_top];
        const int lt = path_len[true_top];
        const int lmin = lp < lt ? lp : lt;
        const int l = lane >> 3;
        const int j = lane & 7;
        float e = 0.0f;
        int sz = 0;
        if (l < lmin) {
            const int st = sib_start[true_top * D + l];
            sz = sib_size[true_top * D + l];
            if (j < sz) e = expf(yp[st + j]);
        }
        e += __shfl_xor(e, 1);
        e += __shfl_xor(e, 2);
        e += __shfl_xor(e, 4);
        float contrib = 0.0f;
        if (l < lmin && j == 0) {
            const float s = e + (float)(C - sz);
            const int tix = path_ids[true_top * D + l];
            const float ce = logf(s) - yp[tix];
            const float lw = expf(-DEPTH_PARAM * (float)(lt - l - 1));
            contrib = lw * ce;
        }
        contrib += __shfl_xor(contrib, 8);
        contrib += __shfl_xor(contrib, 16);
        contrib += __shfl_xor(contrib, 32);
        if (lane == 0) {
            const float diff = fabsf((float)(lp - lt));
            const float total = contrib * (LENGTH_PENALTY * diff) * class_weights[true_top];
            atomicAdd(out, total / (float)Bsz);
        }
    }
}

extern "C" void kernel_launch(void* const* d_in, const int* in_sizes, int n_in,
                              void* d_out, int out_size, void* d_ws, size_t ws_size,
                              hipStream_t stream) {
    const float* y_pred        = (const float*)d_in[0];
    const float* y_true        = (const float*)d_in[1];
    const float* class_weights = (const float*)d_in[2];
    const int*   path_ids      = (const int*)d_in[3];
    const int*   path_len      = (const int*)d_in[4];
    const int*   sib_start     = (const int*)d_in[5];
    const int*   sib_size      = (const int*)d_in[6];
    float* out = (float*)d_out;

    const int C = in_sizes[2];            // 2728
    const int D = in_sizes[3] / C;        // 5
    const int B = in_sizes[0] / C;        // 4096

    const int grid = (B + 1) / 2;         // 2 rows/block, 2 waves/row
    init_out_kernel<<<1, 1, 0, stream>>>(out);
    if (C == 2728) {
        hier_row_kernel_t<2728><<<grid, 256, 0, stream>>>(
            y_pred, y_true, class_weights, path_ids, path_len,
            sib_start, sib_size, out, D, B);
    } else {
        hier_row_kernel_g<<<grid, 256, 0, stream>>>(
            y_pred, y_true, class_weights, path_ids, path_len,
            sib_start, sib_size, out, C, D, B);
    }
}